// Round 1
// baseline (306.492 us; speedup 1.0000x reference)
//
#include <hip/hip_runtime.h>
#include <hip/hip_bf16.h>
#include <stdint.h>

#define DM 1024
#define DF 2048
#define NTOK 8192

typedef float f32x4 __attribute__((ext_vector_type(4)));
typedef short s16x8 __attribute__((ext_vector_type(8)));   // 8 bf16 in 4 VGPRs (per guide §3)

__device__ __forceinline__ unsigned short f2bf(float f) {
    union { float f; unsigned int u; } v; v.f = f;
    unsigned int r = v.u + 0x7fffu + ((v.u >> 16) & 1u);   // RNE
    return (unsigned short)(r >> 16);
}

__device__ __forceinline__ void gload_lds16(const void* g, void* l) {
    __builtin_amdgcn_global_load_lds(
        (const __attribute__((address_space(1))) unsigned int*)g,
        (__attribute__((address_space(3))) unsigned int*)l, 16, 0, 0);
}

// ---------------- kernel 1: zero output (+lbl) and counters ----------------
__global__ __launch_bounds__(256) void zero_out_kernel(float* __restrict__ out,
                                                       int* __restrict__ counts) {
    size_t i = (size_t)blockIdx.x * blockDim.x + threadIdx.x;
    const size_t n4 = ((size_t)NTOK * DM) / 4;
    float4 z = make_float4(0.f, 0.f, 0.f, 0.f);
    for (size_t j = i; j < n4; j += (size_t)gridDim.x * blockDim.x)
        ((float4*)out)[j] = z;
    if (i == 0) { out[(size_t)NTOK * DM] = 0.0f; counts[0] = 0; counts[1] = 0; }
}

// ---------------- kernel 2: x fp32 -> bf16 ----------------
__global__ __launch_bounds__(256) void cvt_x_kernel(const float* __restrict__ x,
                                                    unsigned short* __restrict__ xb) {
    size_t i = (size_t)blockIdx.x * blockDim.x + threadIdx.x;
    const size_t n4 = (size_t)NTOK * DM / 4;
    for (size_t j = i; j < n4; j += (size_t)gridDim.x * blockDim.x) {
        float4 v = ((const float4*)x)[j];
        ushort4 o;
        o.x = f2bf(v.x); o.y = f2bf(v.y); o.z = f2bf(v.z); o.w = f2bf(v.w);
        ((ushort4*)xb)[j] = o;
    }
}

// ---------------- kernel 3: w1/w2 experts {0,1} -> bf16 transposed [n][k] ----------------
__global__ __launch_bounds__(256) void cvt_wT_kernel(const float* __restrict__ w1,
                                                     const float* __restrict__ w2,
                                                     unsigned short* __restrict__ w1t,
                                                     unsigned short* __restrict__ w2t) {
    const int z = blockIdx.z; const int e = z & 1; const int is2 = z >> 1;
    const int R = is2 ? DF : DM;   // src rows (k-dim)
    const int C = is2 ? DM : DF;   // src cols (n-dim)
    const int r0 = blockIdx.y * 64, c0 = blockIdx.x * 64;
    if (r0 >= R || c0 >= C) return;
    const float* src = is2 ? (w2 + (size_t)e * DF * DM) : (w1 + (size_t)e * DM * DF);
    unsigned short* dst = is2 ? (w2t + (size_t)e * DM * DF) : (w1t + (size_t)e * DM * DF);
    __shared__ float tile[64][65];
    const int tc = threadIdx.x & 63;
    const int tr = threadIdx.x >> 6;
    for (int rr = tr; rr < 64; rr += 4)
        tile[rr][tc] = src[(size_t)(r0 + rr) * C + (c0 + tc)];
    __syncthreads();
    for (int rr = tr; rr < 64; rr += 4)
        dst[(size_t)(c0 + rr) * R + (r0 + tc)] = f2bf(tile[tc][rr]);
}

// ---------------- kernel 4: gating (1 wave per token) ----------------
__global__ __launch_bounds__(256) void gate_kernel(const float* __restrict__ x,
                                                   const float* __restrict__ gw,
                                                   const float* __restrict__ gb,
                                                   int* __restrict__ counts,
                                                   int* __restrict__ lists,
                                                   float* __restrict__ sls) {
    const int wv = threadIdx.x >> 6, lane = threadIdx.x & 63;
    const int t = blockIdx.x * 4 + wv;
    const float* xr = x + (size_t)t * DM;
    float acc[8];
#pragma unroll
    for (int e = 0; e < 8; ++e) acc[e] = 0.f;
    for (int i = 0; i < DM / 64; ++i) {
        int d = lane + (i << 6);
        float xv = xr[d];
        float4 g0 = ((const float4*)(gw + (size_t)d * 8))[0];
        float4 g1 = ((const float4*)(gw + (size_t)d * 8))[1];
        acc[0] += xv * g0.x; acc[1] += xv * g0.y; acc[2] += xv * g0.z; acc[3] += xv * g0.w;
        acc[4] += xv * g1.x; acc[5] += xv * g1.y; acc[6] += xv * g1.z; acc[7] += xv * g1.w;
    }
#pragma unroll
    for (int off = 32; off > 0; off >>= 1) {
#pragma unroll
        for (int e = 0; e < 8; ++e) acc[e] += __shfl_xor(acc[e], off, 64);
    }
    if (lane == 0) {
        float lg[8];
#pragma unroll
        for (int e = 0; e < 8; ++e) lg[e] = acc[e] + gb[e];
        int b1i = 0; float b1v = lg[0];
#pragma unroll
        for (int e = 1; e < 8; ++e) if (lg[e] > b1v) { b1v = lg[e]; b1i = e; }
        int b2i = -1; float b2v = -3.4e38f;
#pragma unroll
        for (int e = 0; e < 8; ++e) if (e != b1i && lg[e] > b2v) { b2v = lg[e]; b2i = e; }
        float den = 0.f;
#pragma unroll
        for (int e = 0; e < 8; ++e) den += expf(lg[e] - b1v);
        if (b1i == 0) {                       // top-1 slot matches expert 0
            float s0 = expf(lg[0] - b1v) / den;
            int p = atomicAdd(&counts[0], 1);
            lists[p] = t; sls[p] = s0;
        }
        if (b2i == 1) {                       // top-2 slot matches expert 1
            float s1 = expf(lg[1] - b1v) / den;
            int p = atomicAdd(&counts[1], 1);
            lists[NTOK + p] = t; sls[NTOK + p] = s1;
        }
    }
}

// ---------------- kernels 5/6: tiled MFMA GEMM (128x128x32), gathered rows ----------------
// STAGE2=false: h = gelu(Xg @ W1 + b1) -> hout (bf16 [Ne][DF])
// STAGE2=true : out[tok] += scale * (h @ W2 + b2)   (fp32 atomicAdd scatter)
template <bool STAGE2>
__global__ __launch_bounds__(256) void moe_gemm(const unsigned short* __restrict__ Aglob,
                                                const unsigned short* __restrict__ Bglob,
                                                const float* __restrict__ bias,
                                                unsigned short* __restrict__ hout,
                                                float* __restrict__ outp,
                                                const int* __restrict__ counts,
                                                const int* __restrict__ lists,
                                                const float* __restrict__ sls) {
    constexpr int K = STAGE2 ? DF : DM;
    const int e = blockIdx.z;
    const int Ne = counts[e];
    const int m0 = blockIdx.y * 128;
    if (m0 >= Ne) return;
    const int n0 = blockIdx.x * 128;
    const int tid = threadIdx.x;
    const int lane = tid & 63, wv = tid >> 6;
    const int wr = wv >> 1, wc = wv & 1;
    const int lm = lane & 15, qk = lane >> 4;

    const int* list = lists + e * NTOK;
    const unsigned short* Ae = STAGE2 ? (Aglob + (size_t)e * NTOK * DF) : Aglob;
    const unsigned short* Be = Bglob + (size_t)e * DM * DF;

    __shared__ unsigned short As[128 * 32];
    __shared__ unsigned short Bs[128 * 32];

    // Per-thread staging sources. Chunk c -> LDS slot c*16B (forced by global_load_lds).
    // XOR-swizzle the SOURCE chunk (q ^ ((row>>1)&3)) so fragment reads are 2-way-max on banks.
    const unsigned short* srcA[2];
    const unsigned short* srcB[2];
#pragma unroll
    for (int r = 0; r < 2; ++r) {
        int c = tid + r * 256;
        int row = c >> 2;
        int q = (c & 3) ^ ((row >> 1) & 3);
        int rg = m0 + row;
        if (rg >= Ne) rg = m0;               // clamp: valid data, epilogue-guarded
        size_t arow = STAGE2 ? (size_t)rg * K : (size_t)list[rg] * K;
        srcA[r] = Ae + arow + q * 8;
        srcB[r] = Be + (size_t)(n0 + row) * K + q * 8;
    }

    f32x4 acc[4][4];
#pragma unroll
    for (int i = 0; i < 4; ++i)
#pragma unroll
        for (int j = 0; j < 4; ++j) acc[i][j] = (f32x4){0.f, 0.f, 0.f, 0.f};

    for (int k0 = 0; k0 < K; k0 += 32) {
#pragma unroll
        for (int r = 0; r < 2; ++r) {
            gload_lds16(srcA[r], &As[(r * 256 + wv * 64) * 8]);
            gload_lds16(srcB[r], &Bs[(r * 256 + wv * 64) * 8]);
            srcA[r] += 32; srcB[r] += 32;
        }
        __syncthreads();                      // drains vmcnt -> staging visible
        s16x8 af[4], bfr[4];
#pragma unroll
        for (int am = 0; am < 4; ++am) {
            int ml = wr * 64 + am * 16 + lm;
            int ch = qk ^ ((ml >> 1) & 3);
            af[am] = *(const s16x8*)&As[ml * 32 + ch * 8];
        }
#pragma unroll
        for (int bn = 0; bn < 4; ++bn) {
            int nl = wc * 64 + bn * 16 + lm;
            int ch = qk ^ ((nl >> 1) & 3);
            bfr[bn] = *(const s16x8*)&Bs[nl * 32 + ch * 8];
        }
#pragma unroll
        for (int am = 0; am < 4; ++am)
#pragma unroll
            for (int bn = 0; bn < 4; ++bn)
                acc[am][bn] = __builtin_amdgcn_mfma_f32_16x16x32_bf16(af[am], bfr[bn], acc[am][bn], 0, 0, 0);
        __syncthreads();                      // LDS reads done before next staging
    }

    if (!STAGE2) {
        const float* be = bias + e * DF;
        unsigned short* he = hout + (size_t)e * NTOK * DF;
#pragma unroll
        for (int am = 0; am < 4; ++am) {
#pragma unroll
            for (int bn = 0; bn < 4; ++bn) {
                int ng = n0 + wc * 64 + bn * 16 + lm;      // C/D: col = lane&15
                float bb = be[ng];
                f32x4 v = acc[am][bn];
#pragma unroll
                for (int r = 0; r < 4; ++r) {
                    int ml = wr * 64 + am * 16 + qk * 4 + r;  // C/D: row = (lane>>4)*4+reg
                    int rg = m0 + ml;
                    if (rg < Ne) {
                        float tpre = v[r] + bb;
                        float g = 0.5f * tpre * (1.0f + erff(tpre * 0.70710678118654752f));
                        he[(size_t)rg * DF + ng] = f2bf(g);
                    }
                }
            }
        }
    } else {
        const float* be = bias + e * DM;
        const float* sl = sls + e * NTOK;
#pragma unroll
        for (int am = 0; am < 4; ++am) {
#pragma unroll
            for (int bn = 0; bn < 4; ++bn) {
                int ng = n0 + wc * 64 + bn * 16 + lm;
                float bb = be[ng];
                f32x4 v = acc[am][bn];
#pragma unroll
                for (int r = 0; r < 4; ++r) {
                    int ml = wr * 64 + am * 16 + qk * 4 + r;
                    int rg = m0 + ml;
                    if (rg < Ne) {
                        int tok = list[rg];
                        float s = sl[rg];
                        atomicAdd(&outp[(size_t)tok * DM + ng], s * (v[r] + bb));
                    }
                }
            }
        }
    }
}

extern "C" void kernel_launch(void* const* d_in, const int* in_sizes, int n_in,
                              void* d_out, int out_size, void* d_ws, size_t ws_size,
                              hipStream_t stream) {
    const float* x  = (const float*)d_in[0];
    const float* gw = (const float*)d_in[1];
    const float* gb = (const float*)d_in[2];
    const float* w1 = (const float*)d_in[3];
    const float* b1 = (const float*)d_in[4];
    const float* w2 = (const float*)d_in[5];
    const float* b2 = (const float*)d_in[6];
    float* out = (float*)d_out;
    char* ws = (char*)d_ws;

    // ws layout (bytes): [0] counts, [1024] lists[2][8192], [66560] sls[2][8192],
    // [262144] xb bf16[8192*1024], [+16MiB] w1t bf16[2][2048][1024],
    // [+8MiB] w2t bf16[2][1024][2048], [+8MiB] h bf16[2][8192][2048].  Total ~96.3 MB.
    int*            counts = (int*)(ws + 0);
    int*            lists  = (int*)(ws + 1024);
    float*          sls    = (float*)(ws + 1024 + 65536);
    unsigned short* xb     = (unsigned short*)(ws + 262144);
    unsigned short* w1t    = (unsigned short*)(ws + 262144 + 16777216);
    unsigned short* w2t    = (unsigned short*)(ws + 262144 + 16777216 + 8388608);
    unsigned short* hbuf   = (unsigned short*)(ws + 262144 + 16777216 + 16777216);

    zero_out_kernel<<<1024, 256, 0, stream>>>(out, counts);
    cvt_x_kernel<<<2048, 256, 0, stream>>>(x, xb);
    cvt_wT_kernel<<<dim3(32, 32, 4), 256, 0, stream>>>(w1, w2, w1t, w2t);
    gate_kernel<<<NTOK / 4, 256, 0, stream>>>(x, gw, gb, counts, lists, sls);
    moe_gemm<false><<<dim3(DF / 128, NTOK / 128, 2), 256, 0, stream>>>(xb, w1t, b1, hbuf, nullptr, counts, lists, sls);
    moe_gemm<true><<<dim3(DM / 128, NTOK / 128, 2), 256, 0, stream>>>(hbuf, w2t, b2, nullptr, out, counts, lists, sls);
}

// Round 2
// 281.787 us; speedup vs baseline: 1.0877x; 1.0877x over previous
//
#include <hip/hip_runtime.h>
#include <hip/hip_bf16.h>
#include <stdint.h>

#define DM 1024
#define DF 2048
#define NTOK 8192

typedef float f32x4 __attribute__((ext_vector_type(4)));
typedef short s16x8 __attribute__((ext_vector_type(8)));   // 8 bf16 in 4 VGPRs

__device__ __forceinline__ unsigned short f2bf(float f) {
    union { float f; unsigned int u; } v; v.f = f;
    unsigned int r = v.u + 0x7fffu + ((v.u >> 16) & 1u);   // RNE
    return (unsigned short)(r >> 16);
}

__device__ __forceinline__ void gload_lds16(const void* g, void* l) {
    __builtin_amdgcn_global_load_lds(
        (const __attribute__((address_space(1))) unsigned int*)g,
        (__attribute__((address_space(3))) unsigned int*)l, 16, 0, 0);
}

// ---------------- kernel 1: w1/w2 experts {0,1} -> bf16 transposed [n][k]; zero counts ----------------
__global__ __launch_bounds__(256) void cvt_wT_kernel(const float* __restrict__ w1,
                                                     const float* __restrict__ w2,
                                                     unsigned short* __restrict__ w1t,
                                                     unsigned short* __restrict__ w2t,
                                                     int* __restrict__ counts) {
    if (blockIdx.x == 0 && blockIdx.y == 0 && blockIdx.z == 0 && threadIdx.x == 0) {
        counts[0] = 0; counts[1] = 0;
    }
    const int z = blockIdx.z; const int e = z & 1; const int is2 = z >> 1;
    const int R = is2 ? DF : DM;   // src rows (k-dim)
    const int C = is2 ? DM : DF;   // src cols (n-dim)
    const int r0 = blockIdx.y * 64, c0 = blockIdx.x * 64;
    if (r0 >= R || c0 >= C) return;
    const float* src = is2 ? (w2 + (size_t)e * DF * DM) : (w1 + (size_t)e * DM * DF);
    unsigned short* dst = is2 ? (w2t + (size_t)e * DM * DF) : (w1t + (size_t)e * DM * DF);
    __shared__ float tile[64][65];
    const int tc = threadIdx.x & 63;
    const int tr = threadIdx.x >> 6;
    for (int rr = tr; rr < 64; rr += 4)
        tile[rr][tc] = src[(size_t)(r0 + rr) * C + (c0 + tc)];
    __syncthreads();
    for (int rr = tr; rr < 64; rr += 4)
        dst[(size_t)(c0 + rr) * R + (r0 + tc)] = f2bf(tile[tc][rr]);
}

// ---------------- kernel 2: fused zero-out + x->bf16 + gating (1 wave per token) ----------------
__global__ __launch_bounds__(256) void prep_kernel(const float* __restrict__ x,
                                                   const float* __restrict__ gw,
                                                   const float* __restrict__ gb,
                                                   unsigned short* __restrict__ xb,
                                                   float* __restrict__ out,
                                                   int* __restrict__ counts,
                                                   int* __restrict__ lists,
                                                   float* __restrict__ sls) {
    const int wv = threadIdx.x >> 6, lane = threadIdx.x & 63;
    const int t = blockIdx.x * 4 + wv;
    const float* xr = x + (size_t)t * DM;
    unsigned short* xbr = xb + (size_t)t * DM;
    float* outr = out + (size_t)t * DM;
    float acc[8];
#pragma unroll
    for (int e = 0; e < 8; ++e) acc[e] = 0.f;
    const float4 z4 = make_float4(0.f, 0.f, 0.f, 0.f);
#pragma unroll
    for (int i = 0; i < 4; ++i) {
        const int c4 = i * 64 + lane;                 // float4 index within the 256-float4 row
        float4 v = ((const float4*)xr)[c4];
        ushort4 o;
        o.x = f2bf(v.x); o.y = f2bf(v.y); o.z = f2bf(v.z); o.w = f2bf(v.w);
        ((ushort4*)xbr)[c4] = o;
        ((float4*)outr)[c4] = z4;
        const float xs[4] = {v.x, v.y, v.z, v.w};
        const float* g = gw + (size_t)c4 * 32;        // = d0*8 floats, d0 = c4*4
#pragma unroll
        for (int jj = 0; jj < 4; ++jj) {
            float4 ga = ((const float4*)(g + jj * 8))[0];
            float4 gbv = ((const float4*)(g + jj * 8 + 4))[0];
            acc[0] += xs[jj] * ga.x;  acc[1] += xs[jj] * ga.y;
            acc[2] += xs[jj] * ga.z;  acc[3] += xs[jj] * ga.w;
            acc[4] += xs[jj] * gbv.x; acc[5] += xs[jj] * gbv.y;
            acc[6] += xs[jj] * gbv.z; acc[7] += xs[jj] * gbv.w;
        }
    }
#pragma unroll
    for (int off = 32; off > 0; off >>= 1) {
#pragma unroll
        for (int e = 0; e < 8; ++e) acc[e] += __shfl_xor(acc[e], off, 64);
    }
    if (lane == 0) {
        float lg[8];
#pragma unroll
        for (int e = 0; e < 8; ++e) lg[e] = acc[e] + gb[e];
        int b1i = 0; float b1v = lg[0];
#pragma unroll
        for (int e = 1; e < 8; ++e) if (lg[e] > b1v) { b1v = lg[e]; b1i = e; }
        int b2i = -1; float b2v = -3.4e38f;
#pragma unroll
        for (int e = 0; e < 8; ++e) if (e != b1i && lg[e] > b2v) { b2v = lg[e]; b2i = e; }
        float den = 0.f;
#pragma unroll
        for (int e = 0; e < 8; ++e) den += expf(lg[e] - b1v);
        if (b1i == 0) {                       // top-1 slot matches expert 0
            float s0 = expf(lg[0] - b1v) / den;
            int p = atomicAdd(&counts[0], 1);
            lists[p] = t; sls[p] = s0;
        }
        if (b2i == 1) {                       // top-2 slot matches expert 1
            float s1 = expf(lg[1] - b1v) / den;
            int p = atomicAdd(&counts[1], 1);
            lists[NTOK + p] = t; sls[NTOK + p] = s1;
        }
    }
    if (blockIdx.x == 0 && threadIdx.x == 0) out[(size_t)NTOK * DM] = 0.0f;  // lbl == 0 exactly
}

// ---------------- kernels 3/4: pipelined MFMA GEMM, double-buffered LDS, raw barriers ----------------
// STAGE2=false: h = gelu(Xg @ W1 + b1) -> hout (bf16 [Ne][DF])
// STAGE2=true : out[tok] += scale * (h @ W2 + b2)   (fp32 atomicAdd scatter)
template <int TM, int TN, bool STAGE2>
__global__ __launch_bounds__(256) void moe_gemm(const unsigned short* __restrict__ Aglob,
                                                const unsigned short* __restrict__ Bglob,
                                                const float* __restrict__ bias,
                                                unsigned short* __restrict__ hout,
                                                float* __restrict__ outp,
                                                const int* __restrict__ counts,
                                                const int* __restrict__ lists,
                                                const float* __restrict__ sls) {
    constexpr int K  = STAGE2 ? DF : DM;
    constexpr int NS = K / 32;            // k-steps (even)
    constexpr int CA = TM / 64;           // A 16B-chunks per thread per step
    constexpr int CB = TN / 64;
    constexpr int FM = TM / 32;           // m-fragments per wave (wave owns TM/2 rows)
    constexpr int FN = TN / 32;
    const int e = blockIdx.z;
    const int Ne = counts[e];
    const int m0 = blockIdx.y * TM;
    if (m0 >= Ne) return;
    const int n0 = blockIdx.x * TN;
    const int tid = threadIdx.x;
    const int lane = tid & 63, wv = tid >> 6;
    const int wr = wv >> 1, wc = wv & 1;
    const int lm = lane & 15, qk = lane >> 4;

    const int* list = lists + e * NTOK;
    const unsigned short* Ae = STAGE2 ? (Aglob + (size_t)e * NTOK * DF) : Aglob;
    const unsigned short* Be = Bglob + (size_t)e * DM * DF;

    __shared__ alignas(16) unsigned short As[2][TM * 32];
    __shared__ alignas(16) unsigned short Bs[2][TN * 32];

    // Per-thread staging sources; LDS slot is forced to chunk_idx*16B by global_load_lds,
    // so we XOR-swizzle the SOURCE chunk (q ^ ((row>>1)&3)) -> fragment reads are 2-way max.
    const unsigned short* srcA[CA];
    const unsigned short* srcB[CB];
#pragma unroll
    for (int r = 0; r < CA; ++r) {
        int c = tid + r * 256;
        int row = c >> 2;
        int q = (c & 3) ^ ((row >> 1) & 3);
        int rg = m0 + row;
        if (rg >= Ne) rg = m0;               // clamp: valid data, epilogue-guarded
        size_t arow = STAGE2 ? (size_t)rg * K : (size_t)list[rg] * K;
        srcA[r] = Ae + arow + q * 8;
    }
#pragma unroll
    for (int r = 0; r < CB; ++r) {
        int c = tid + r * 256;
        int row = c >> 2;
        int q = (c & 3) ^ ((row >> 1) & 3);
        srcB[r] = Be + (size_t)(n0 + row) * K + q * 8;
    }

    f32x4 acc[FM][FN];
#pragma unroll
    for (int i = 0; i < FM; ++i)
#pragma unroll
        for (int j = 0; j < FN; ++j) acc[i][j] = (f32x4){0.f, 0.f, 0.f, 0.f};

    auto issue = [&](int buf) {
#pragma unroll
        for (int r = 0; r < CA; ++r) {
            gload_lds16(srcA[r], &As[buf][(r * 256 + wv * 64) * 8]);
            srcA[r] += 32;
        }
#pragma unroll
        for (int r = 0; r < CB; ++r) {
            gload_lds16(srcB[r], &Bs[buf][(r * 256 + wv * 64) * 8]);
            srcB[r] += 32;
        }
    };
    auto compute = [&](int buf) {
        s16x8 af[FM], bfr[FN];
#pragma unroll
        for (int am = 0; am < FM; ++am) {
            int ml = wr * (TM / 2) + am * 16 + lm;
            int ch = qk ^ ((ml >> 1) & 3);
            af[am] = *(const s16x8*)&As[buf][ml * 32 + ch * 8];
        }
#pragma unroll
        for (int bn = 0; bn < FN; ++bn) {
            int nl = wc * (TN / 2) + bn * 16 + lm;
            int ch = qk ^ ((nl >> 1) & 3);
            bfr[bn] = *(const s16x8*)&Bs[buf][nl * 32 + ch * 8];
        }
#pragma unroll
        for (int am = 0; am < FM; ++am)
#pragma unroll
            for (int bn = 0; bn < FN; ++bn)
                acc[am][bn] = __builtin_amdgcn_mfma_f32_16x16x32_bf16(af[am], bfr[bn], acc[am][bn], 0, 0, 0);
    };

    issue(0);                                 // preload tile 0
#pragma unroll 1
    for (int ks = 0; ks < NS; ks += 2) {
        // phase A: prefetch tile ks+1 into buf1, compute tile ks from buf0
        if (ks + 1 < NS) {
            issue(1);
            asm volatile("s_waitcnt vmcnt(%0)" :: "n"(CA + CB) : "memory");
        } else {
            asm volatile("s_waitcnt vmcnt(0)" ::: "memory");
        }
        __builtin_amdgcn_s_barrier();
        asm volatile("" ::: "memory");
        compute(0);
        asm volatile("" ::: "memory");
        __builtin_amdgcn_s_barrier();
        // phase B: prefetch tile ks+2 into buf0, compute tile ks+1 from buf1
        if (ks + 2 < NS) {
            issue(0);
            asm volatile("s_waitcnt vmcnt(%0)" :: "n"(CA + CB) : "memory");
        } else {
            asm volatile("s_waitcnt vmcnt(0)" ::: "memory");
        }
        __builtin_amdgcn_s_barrier();
        asm volatile("" ::: "memory");
        compute(1);
        asm volatile("" ::: "memory");
        __builtin_amdgcn_s_barrier();
    }

    if (!STAGE2) {
        const float* be = bias + e * DF;
        unsigned short* he = hout + (size_t)e * NTOK * DF;
#pragma unroll
        for (int am = 0; am < FM; ++am) {
#pragma unroll
            for (int bn = 0; bn < FN; ++bn) {
                int ng = n0 + wc * (TN / 2) + bn * 16 + lm;   // C/D: col = lane&15
                float bb = be[ng];
                f32x4 v = acc[am][bn];
#pragma unroll
                for (int r = 0; r < 4; ++r) {
                    int ml = wr * (TM / 2) + am * 16 + qk * 4 + r;  // C/D: row = (lane>>4)*4+reg
                    int rg = m0 + ml;
                    if (rg < Ne) {
                        float tpre = v[r] + bb;
                        float g = 0.5f * tpre * (1.0f + erff(tpre * 0.70710678118654752f));
                        he[(size_t)rg * DF + ng] = f2bf(g);
                    }
                }
            }
        }
    } else {
        const float* be = bias + e * DM;
        const float* sl = sls + e * NTOK;
#pragma unroll
        for (int am = 0; am < FM; ++am) {
#pragma unroll
            for (int bn = 0; bn < FN; ++bn) {
                int ng = n0 + wc * (TN / 2) + bn * 16 + lm;
                float bb = be[ng];
                f32x4 v = acc[am][bn];
#pragma unroll
                for (int r = 0; r < 4; ++r) {
                    int ml = wr * (TM / 2) + am * 16 + qk * 4 + r;
                    int rg = m0 + ml;
                    if (rg < Ne) {
                        int tok = list[rg];
                        float s = sl[rg];
                        atomicAdd(&outp[(size_t)tok * DM + ng], s * (v[r] + bb));
                    }
                }
            }
        }
    }
}

extern "C" void kernel_launch(void* const* d_in, const int* in_sizes, int n_in,
                              void* d_out, int out_size, void* d_ws, size_t ws_size,
                              hipStream_t stream) {
    const float* x  = (const float*)d_in[0];
    const float* gw = (const float*)d_in[1];
    const float* gb = (const float*)d_in[2];
    const float* w1 = (const float*)d_in[3];
    const float* b1 = (const float*)d_in[4];
    const float* w2 = (const float*)d_in[5];
    const float* b2 = (const float*)d_in[6];
    float* out = (float*)d_out;
    char* ws = (char*)d_ws;

    // ws layout (bytes): [0] counts, [1024] lists[2][8192], [66560] sls[2][8192],
    // [262144] xb bf16[8192*1024], [+16MiB] w1t bf16[2][2048][1024],
    // [+8MiB] w2t bf16[2][1024][2048], [+8MiB] h bf16[2][8192][2048].  Total ~96.3 MB.
    int*            counts = (int*)(ws + 0);
    int*            lists  = (int*)(ws + 1024);
    float*          sls    = (float*)(ws + 1024 + 65536);
    unsigned short* xb     = (unsigned short*)(ws + 262144);
    unsigned short* w1t    = (unsigned short*)(ws + 262144 + 16777216);
    unsigned short* w2t    = (unsigned short*)(ws + 262144 + 16777216 + 8388608);
    unsigned short* hbuf   = (unsigned short*)(ws + 262144 + 16777216 + 16777216);

    cvt_wT_kernel<<<dim3(32, 32, 4), 256, 0, stream>>>(w1, w2, w1t, w2t, counts);
    prep_kernel<<<NTOK / 4, 256, 0, stream>>>(x, gw, gb, xb, out, counts, lists, sls);
    moe_gemm<128, 64, false><<<dim3(DF / 64, NTOK / 128, 2), 256, 0, stream>>>(xb, w1t, b1, hbuf, nullptr, counts, lists, sls);
    moe_gemm<64, 64, true><<<dim3(DM / 64, NTOK / 64, 2), 256, 0, stream>>>(hbuf, w2t, b2, nullptr, out, counts, lists, sls);
}